// Round 1
// baseline (129.987 us; speedup 1.0000x reference)
//
#include <hip/hip_runtime.h>

// StructureTensorEffect: B=4, C=3, H=W=1024, fp32.
// px = x + OFF_U[t]*sigma, py = y + OFF_V[t]*sigma  (exact for pow-2 W,H)
// -> bilinear fracs are per-(batch,class) constants; classes {-s, 0, +s}.
// Factorized: per channel, horizontal lerps h_m/h_p on column pairs at 5 rows,
// center column direct loads at 4 rows; vertical lerps produce the 8 taps.

#define W_ 1024
#define H_ 1024

__device__ __forceinline__ float lerp1(float a, float b, float f) {
    return fmaf(f, b - a, a);
}

__global__ __launch_bounds__(256) void st_kernel(
    const float* __restrict__ X, const float* __restrict__ S,
    float* __restrict__ O)
{
    int idx = blockIdx.x * 256 + threadIdx.x;
    int b   = idx >> 20;           // H*W = 1<<20
    int rem = idx & 0xFFFFF;
    int y   = rem >> 10;
    int xi  = rem & 1023;

    float sg = S[b];
    float imf = floorf(-sg), ipf = floorf(sg);
    float fm  = -sg - imf;         // frac for the -sigma class
    float fp  =  sg - ipf;         // frac for the +sigma class
    int   im  = (int)imf, ip = (int)ipf;

    // clamped column indices (reference: clip(x0), then clip(x0i+1))
    int cm0 = min(max(xi + im, 0), W_ - 1), cm1 = min(cm0 + 1, W_ - 1);
    int cp0 = min(max(xi + ip, 0), W_ - 1), cp1 = min(cp0 + 1, W_ - 1);
    // clamped row indices
    int rm0 = min(max(y + im, 0), H_ - 1),  rm1 = min(rm0 + 1, H_ - 1);
    int rp0 = min(max(y + ip, 0), H_ - 1),  rp1 = min(rp0 + 1, H_ - 1);

    int o_rm0 = rm0 << 10, o_rm1 = rm1 << 10;
    int o_rp0 = rp0 << 10, o_rp1 = rp1 << 10;
    int o_r0  = y   << 10;

    float oxx = 0.f, oyy = 0.f, oxy = 0.f;

    #pragma unroll
    for (int c = 0; c < 3; ++c) {
        const float* base = X + (((size_t)(b * 3 + c)) << 20);

        // horizontal lerps, minus-class columns, 5 rows
        float hm_m0 = lerp1(base[o_rm0 + cm0], base[o_rm0 + cm1], fm);
        float hm_m1 = lerp1(base[o_rm1 + cm0], base[o_rm1 + cm1], fm);
        float hm_0  = lerp1(base[o_r0  + cm0], base[o_r0  + cm1], fm);
        float hm_p0 = lerp1(base[o_rp0 + cm0], base[o_rp0 + cm1], fm);
        float hm_p1 = lerp1(base[o_rp1 + cm0], base[o_rp1 + cm1], fm);
        // horizontal lerps, plus-class columns, 5 rows
        float hp_m0 = lerp1(base[o_rm0 + cp0], base[o_rm0 + cp1], fp);
        float hp_m1 = lerp1(base[o_rm1 + cp0], base[o_rm1 + cp1], fp);
        float hp_0  = lerp1(base[o_r0  + cp0], base[o_r0  + cp1], fp);
        float hp_p0 = lerp1(base[o_rp0 + cp0], base[o_rp0 + cp1], fp);
        float hp_p1 = lerp1(base[o_rp1 + cp0], base[o_rp1 + cp1], fp);
        // center column (frac = 0 exactly): direct loads at 4 rows
        float h0_m0 = base[o_rm0 + xi], h0_m1 = base[o_rm1 + xi];
        float h0_p0 = base[o_rp0 + xi], h0_p1 = base[o_rp1 + xi];

        // vertical lerps -> the 8 taps
        float t0 = lerp1(hm_m0, hm_m1, fm);   // (-s,-s)
        float t1 = hm_0;                      // (-s, 0)
        float t2 = lerp1(hm_p0, hm_p1, fp);   // (-s,+s)
        float t3 = lerp1(h0_m0, h0_m1, fm);   // ( 0,-s)
        float t4 = lerp1(h0_p0, h0_p1, fp);   // ( 0,+s)
        float t5 = lerp1(hp_m0, hp_m1, fm);   // (+s,-s)
        float t6 = hp_0;                      // (+s, 0)
        float t7 = lerp1(hp_p0, hp_p1, fp);   // (+s,+s)

        // KU = [-.25,-.5,-.25,0,0,.25,.5,.25], KV = [-.25,0,.25,-.5,.5,-.25,0,.25]
        float su = 0.25f * (t5 + t7 - t0 - t2) + 0.5f * (t6 - t1);
        float sv = 0.25f * (t2 + t7 - t0 - t5) + 0.5f * (t4 - t3);

        float l2 = (c == 0) ? 10000.f : 1.f;  // lum^2
        oxx = fmaf(l2 * su, su, oxx);
        oyy = fmaf(l2 * sv, sv, oyy);
        oxy = fmaf(l2 * su, sv, oxy);
    }

    size_t obase = ((size_t)(b * 3)) << 20;
    int pix = (y << 10) | xi;
    O[obase + pix]             = oxx;
    O[obase + (1 << 20) + pix] = oyy;
    O[obase + (2 << 20) + pix] = oxy;
}

extern "C" void kernel_launch(void* const* d_in, const int* in_sizes, int n_in,
                              void* d_out, int out_size, void* d_ws, size_t ws_size,
                              hipStream_t stream) {
    const float* x     = (const float*)d_in[0];
    const float* sigma = (const float*)d_in[1];
    float* out = (float*)d_out;

    // 4 * 1024 * 1024 pixels, one thread each
    dim3 grid(4 * 1024 * 1024 / 256), block(256);
    hipLaunchKernelGGL(st_kernel, grid, block, 0, stream, x, sigma, out);
}